// Round 8
// baseline (2068.452 us; speedup 1.0000x reference)
//
#include <hip/hip_runtime.h>
#include <hip/hip_bf16.h>

#define DIM 2048
#define BM 256
#define BN 256
#define BK 32
#define KSTEPS (DIM / BK)        // 64 K-tiles
#define TILE_ELEMS (BM * BK)     // 8192 f16 = 16 KB per K-tile per operand

typedef _Float16 f16x8 __attribute__((ext_vector_type(8)));
typedef float f32x4 __attribute__((ext_vector_type(4)));
typedef unsigned long long u64;

typedef const unsigned int __attribute__((address_space(1))) gu32;
typedef unsigned int __attribute__((address_space(3))) lu32;

__device__ __forceinline__ void gl_lds16(const void* g, void* l) {
    __builtin_amdgcn_global_load_lds((gu32*)g, (lu32*)l, 16, 0, 0);
}

// Monotone float->uint map; pack (val, col) so u64 max = (max val, first col on ties)
__device__ __forceinline__ u64 pack_key(float v, unsigned int col) {
    unsigned int b = __float_as_uint(v);
    b ^= (unsigned int)(((int)b >> 31)) | 0x80000000u;
    return ((u64)b << 32) | (u64)(~col);
}
__device__ __forceinline__ u64 umax64(u64 a, u64 b) { return a > b ? a : b; }
__device__ __forceinline__ u64 umin64(u64 a, u64 b) { return a < b ? a : b; }

// lock-free exact top-3 cascade (order-independent => deterministic)
__device__ __forceinline__ void cascade3(u64* r1, u64* r2, u64* r3, u64 k) {
    u64 old = atomicMax(r1, k);
    k = umin64(k, old);
    if (k) {
        old = atomicMax(r2, k);
        k = umin64(k, old);
        if (k) atomicMax(r3, k);
    }
}

// tile image: 128B lines (row pairs), 8x16B slots, slot ^= line&7 (0 conflicts, r7-verified)
__device__ __forceinline__ int tileoff(int row, int kg) {
    const int line = row >> 1;
    const int s8 = ((row & 1) << 2) | kg;
    return line * 64 + ((s8 ^ (line & 7)) << 3);
}

// old swizzle (used by the 128^2 fallback kernel only)
__device__ __forceinline__ int swz(int row, int slot) {
    return row * BK + (slot ^ ((row >> 1) & 3)) * 8;
}

__global__ void vocab_invnorm_kernel(const float* __restrict__ Vg,
                                     float* __restrict__ invnorm) {
    const int v = blockIdx.x;
    const int t = threadIdx.x;
    const float* row = Vg + (size_t)v * DIM;
    float4 f0 = *reinterpret_cast<const float4*>(row + t * 8);
    float4 f1 = *reinterpret_cast<const float4*>(row + t * 8 + 4);
    float s = f0.x*f0.x + f0.y*f0.y + f0.z*f0.z + f0.w*f0.w
            + f1.x*f1.x + f1.y*f1.y + f1.z*f1.z + f1.w*f1.w;
#pragma unroll
    for (int off = 32; off > 0; off >>= 1) s += __shfl_down(s, off);
    __shared__ float ls[4];
    const int lane = t & 63, w = t >> 6;
    if (lane == 0) ls[w] = s;
    __syncthreads();
    if (t == 0) {
        float tot = ls[0] + ls[1] + ls[2] + ls[3];
        invnorm[v] = 1.0f / fmaxf(sqrtf(tot), 1e-12f);
    }
}

// X -> tiled f16 in the line/slot-swizzled image (raw values)
__global__ void convert_x_kernel(const float* __restrict__ X, _Float16* __restrict__ Xh) {
    const int tile = blockIdx.x;          // mblk*64 + ks
    const int mblk = tile >> 6, ks = tile & 63;
    const float* src = X + (size_t)(mblk * BM) * DIM + ks * BK;
    _Float16* dst = Xh + (size_t)tile * TILE_ELEMS;
    const int t = threadIdx.x;
#pragma unroll
    for (int u = 0; u < 4; ++u) {
        const int c = t + u * 256;        // 0..1023 chunk id (linear stage order)
        const int line = c >> 3;
        const int s8 = (c & 7) ^ (line & 7);
        const int row = (line << 1) | (s8 >> 2);
        const int cs = s8 & 3;
        const float* s = src + (size_t)row * DIM + cs * 8;
        float4 f0 = *(const float4*)s, f1 = *(const float4*)(s + 4);
        float xv[8] = {f0.x, f0.y, f0.z, f0.w, f1.x, f1.y, f1.z, f1.w};
        f16x8 h;
#pragma unroll
        for (int e = 0; e < 8; ++e) h[e] = (_Float16)xv[e];
        *(f16x8*)(dst + c * 8) = h;
    }
}

// V -> tiled f16 (same image), pre-normalized by invnorm
__global__ void convert_v_kernel(const float* __restrict__ Vg,
                                 const float* __restrict__ invnorm,
                                 _Float16* __restrict__ Vh) {
    const int tile = blockIdx.x;          // nblk*64 + ks
    const int nblk = tile >> 6, ks = tile & 63;
    const float* src = Vg + (size_t)(nblk * BN) * DIM + ks * BK;
    _Float16* dst = Vh + (size_t)tile * TILE_ELEMS;
    const int t = threadIdx.x;
#pragma unroll
    for (int u = 0; u < 4; ++u) {
        const int c = t + u * 256;
        const int line = c >> 3;
        const int s8 = (c & 7) ^ (line & 7);
        const int row = (line << 1) | (s8 >> 2);
        const int cs = s8 & 3;
        const float sc = invnorm[nblk * BN + row];
        const float* s = src + (size_t)row * DIM + cs * 8;
        float4 f0 = *(const float4*)s, f1 = *(const float4*)(s + 4);
        float xv[8] = {f0.x, f0.y, f0.z, f0.w, f1.x, f1.y, f1.z, f1.w};
        f16x8 h;
#pragma unroll
        for (int e = 0; e < 8; ++e) h[e] = (_Float16)(xv[e] * sc);
        *(f16x8*)(dst + c * 8) = h;
    }
}

#define MFMA16(d, a, b) d = __builtin_amdgcn_mfma_f32_16x16x32_f16(a, b, d, 0, 0, 0)

// 512 threads = 8 waves (2M x 4N), wave tile 128x64, 3-slot K ring (96 KB LDS),
// m201-style 2-phase-per-K-tile schedule: reads || stage || vmcnt(4) || barrier
// || setprio+16 MFMA || barrier.  Stages land 4 phases before their reads.
__global__ __launch_bounds__(512, 2) void sim_f16_phased(
        const _Float16* __restrict__ Xh, const _Float16* __restrict__ Vh,
        u64* __restrict__ R1, u64* __restrict__ R2, u64* __restrict__ R3) {
    __shared__ alignas(16) _Float16 ldsA[3][TILE_ELEMS];   // 48 KB
    __shared__ alignas(16) _Float16 ldsB[3][TILE_ELEMS];   // 48 KB

    const int tid = threadIdx.x;
    // XCD-chunked bijective swizzle: 4000 blocks = 8 x 500
    const int flat = blockIdx.x;
    const int idx  = (flat & 7) * 500 + (flat >> 3);
    const int mblk = idx & 31;           // M/256 = 32
    const int nblk = idx >> 5;           // NV/256 = 125

    const int lane = tid & 63;
    const int w  = tid >> 6;             // 0..7
    const int wm = w >> 2, wn = w & 3;   // 2x4 wave grid; wave tile 128x64
    const int lr = lane & 15;
    const int kg = lane >> 4;

    const _Float16* Atiles = Xh + (size_t)mblk * KSTEPS * TILE_ELEMS;
    const _Float16* Btiles = Vh + (size_t)nblk * KSTEPS * TILE_ELEMS;

    f32x4 acc[8][4] = {};

    int offA[8], offB[4];
#pragma unroll
    for (int i = 0; i < 8; ++i) offA[i] = tileoff(wm * 128 + i * 16 + lr, kg);
#pragma unroll
    for (int j = 0; j < 4; ++j) offB[j] = tileoff(wn * 64 + j * 16 + lr, kg);

    const int c1 = tid * 8;              // staging chunk offsets (16B each)
    const int c2 = (tid + 512) * 8;

    // prologue: stage K-tiles 0,1 into slots 0,1; drain; sync
#pragma unroll
    for (int p = 0; p < 2; ++p) {
        const _Float16* ag = Atiles + (size_t)p * TILE_ELEMS;
        const _Float16* bg = Btiles + (size_t)p * TILE_ELEMS;
        gl_lds16(ag + c1, &ldsA[p][c1]);
        gl_lds16(ag + c2, &ldsA[p][c2]);
        gl_lds16(bg + c1, &ldsB[p][c1]);
        gl_lds16(bg + c2, &ldsB[p][c2]);
    }
    asm volatile("s_waitcnt vmcnt(0)" ::: "memory");
    __builtin_amdgcn_s_barrier();
    __builtin_amdgcn_sched_barrier(0);

    for (int kt = 0; kt < KSTEPS; ++kt) {
        const int slot = kt % 3;
        const int s2   = (kt + 2) % 3;
        const _Float16* As = &ldsA[slot][0];
        const _Float16* Bs = &ldsB[slot][0];
        const _Float16* agN = Atiles + (size_t)(kt + 2) * TILE_ELEMS;
        const _Float16* bgN = Btiles + (size_t)(kt + 2) * TILE_ELEMS;

        // ---------- phase 0: A rows 0..3, all B ----------
        f16x8 a0 = *(const f16x8*)(As + offA[0]);
        f16x8 a1 = *(const f16x8*)(As + offA[1]);
        f16x8 a2 = *(const f16x8*)(As + offA[2]);
        f16x8 a3 = *(const f16x8*)(As + offA[3]);
        f16x8 b0 = *(const f16x8*)(Bs + offB[0]);
        f16x8 b1 = *(const f16x8*)(Bs + offB[1]);
        f16x8 b2 = *(const f16x8*)(Bs + offB[2]);
        f16x8 b3 = *(const f16x8*)(Bs + offB[3]);
        if (kt + 2 < KSTEPS) {
            gl_lds16(agN + c1, &ldsA[s2][c1]);
            gl_lds16(agN + c2, &ldsA[s2][c2]);
            asm volatile("s_waitcnt vmcnt(4)" ::: "memory");
        } else if (kt == KSTEPS - 2) {
            asm volatile("s_waitcnt vmcnt(2)" ::: "memory");
        }
        __builtin_amdgcn_s_barrier();
        __builtin_amdgcn_sched_barrier(0);
        __builtin_amdgcn_s_setprio(1);
        MFMA16(acc[0][0], a0, b0); MFMA16(acc[0][1], a0, b1);
        MFMA16(acc[0][2], a0, b2); MFMA16(acc[0][3], a0, b3);
        MFMA16(acc[1][0], a1, b0); MFMA16(acc[1][1], a1, b1);
        MFMA16(acc[1][2], a1, b2); MFMA16(acc[1][3], a1, b3);
        MFMA16(acc[2][0], a2, b0); MFMA16(acc[2][1], a2, b1);
        MFMA16(acc[2][2], a2, b2); MFMA16(acc[2][3], a2, b3);
        MFMA16(acc[3][0], a3, b0); MFMA16(acc[3][1], a3, b1);
        MFMA16(acc[3][2], a3, b2); MFMA16(acc[3][3], a3, b3);
        __builtin_amdgcn_s_setprio(0);
        __builtin_amdgcn_s_barrier();
        __builtin_amdgcn_sched_barrier(0);

        // ---------- phase 1: A rows 4..7 (B regs still live) ----------
        a0 = *(const f16x8*)(As + offA[4]);
        a1 = *(const f16x8*)(As + offA[5]);
        a2 = *(const f16x8*)(As + offA[6]);
        a3 = *(const f16x8*)(As + offA[7]);
        if (kt + 2 < KSTEPS) {
            gl_lds16(bgN + c1, &ldsB[s2][c1]);
            gl_lds16(bgN + c2, &ldsB[s2][c2]);
            asm volatile("s_waitcnt vmcnt(4)" ::: "memory");
        } else if (kt == KSTEPS - 2) {
            asm volatile("s_waitcnt vmcnt(0)" ::: "memory");
        }
        __builtin_amdgcn_s_barrier();
        __builtin_amdgcn_sched_barrier(0);
        __builtin_amdgcn_s_setprio(1);
        MFMA16(acc[4][0], a0, b0); MFMA16(acc[4][1], a0, b1);
        MFMA16(acc[4][2], a0, b2); MFMA16(acc[4][3], a0, b3);
        MFMA16(acc[5][0], a1, b0); MFMA16(acc[5][1], a1, b1);
        MFMA16(acc[5][2], a1, b2); MFMA16(acc[5][3], a1, b3);
        MFMA16(acc[6][0], a2, b0); MFMA16(acc[6][1], a2, b1);
        MFMA16(acc[6][2], a2, b2); MFMA16(acc[6][3], a2, b3);
        MFMA16(acc[7][0], a3, b0); MFMA16(acc[7][1], a3, b1);
        MFMA16(acc[7][2], a3, b2); MFMA16(acc[7][3], a3, b3);
        __builtin_amdgcn_s_setprio(0);
        __builtin_amdgcn_s_barrier();
        __builtin_amdgcn_sched_barrier(0);
    }

    // epilogue: per-row block top-2 -> global top-3 cascade
    const int m0 = mblk * BM, n0 = nblk * BN;
#pragma unroll
    for (int i = 0; i < 8; ++i) {
#pragma unroll
        for (int r = 0; r < 4; ++r) {
            u64 k[4];
#pragma unroll
            for (int j = 0; j < 4; ++j)
                k[j] = pack_key(acc[i][j][r],
                                (unsigned int)(n0 + wn * 64 + j * 16 + lr));
            u64 m01 = umax64(k[0], k[1]), n01 = umin64(k[0], k[1]);
            u64 m23 = umax64(k[2], k[3]), n23 = umin64(k[2], k[3]);
            u64 a1 = umax64(m01, m23);
            u64 a2 = umax64(umin64(m01, m23), umax64(n01, n23));
#pragma unroll
            for (int mask = 1; mask < 16; mask <<= 1) {
                u64 b1 = __shfl_xor(a1, mask);
                u64 b2 = __shfl_xor(a2, mask);
                u64 t1 = umax64(a1, b1);
                a2 = umax64(umin64(a1, b1), umax64(a2, b2));
                a1 = t1;
            }
            if (lr == 0) {
                const int row = m0 + wm * 128 + i * 16 + kg * 4 + r;
                cascade3(&R1[row], &R2[row], &R3[row], a1);
                cascade3(&R1[row], &R2[row], &R3[row], a2);
            }
        }
    }
}

// ---------------- fallback (verified round-3 path, 128^2; used if ws too small) ----------------
__global__ __launch_bounds__(256) void sim_coarse_fallback(
        const float* __restrict__ X, const float* __restrict__ Vg,
        const float* __restrict__ invnorm,
        u64* __restrict__ R1, u64* __restrict__ R2, u64* __restrict__ R3) {
    __shared__ alignas(16) _Float16 Ah[128 * BK];
    __shared__ alignas(16) _Float16 Bh[128 * BK];
    const int tid = threadIdx.x;
    const int flat = blockIdx.x;
    const int idx  = (flat & 7) * 2000 + (flat >> 3);
    const int panel = idx / 3200;
    const int w_    = idx - panel * 3200;
    const int mblk  = w_ & 63;
    const int nblk  = panel * 50 + (w_ >> 6);
    const int m0 = mblk * 128, n0 = nblk * 128;
    const int lane = tid & 63;
    const int w  = tid >> 6;
    const int wm = w >> 1, wn = w & 1;
    const int lr = lane & 15;
    const int kg = lane >> 4;
    const int sr  = tid >> 2;
    const int skc = tid & 3;
    const float* Aptr0 = X  + (size_t)(m0 + sr)      * DIM + skc * 8;
    const float* Aptr1 = X  + (size_t)(m0 + 64 + sr) * DIM + skc * 8;
    const float* Bptr0 = Vg + (size_t)(n0 + sr)      * DIM + skc * 8;
    const float* Bptr1 = Vg + (size_t)(n0 + 64 + sr) * DIM + skc * 8;
    float4 ra[4], rb[4];
    ra[0] = *(const float4*)(Aptr0);     ra[1] = *(const float4*)(Aptr0 + 4);
    ra[2] = *(const float4*)(Aptr1);     ra[3] = *(const float4*)(Aptr1 + 4);
    rb[0] = *(const float4*)(Bptr0);     rb[1] = *(const float4*)(Bptr0 + 4);
    rb[2] = *(const float4*)(Bptr1);     rb[3] = *(const float4*)(Bptr1 + 4);
    f32x4 acc[4][4] = {};
    const int wA0 = swz(sr, skc), wA1 = swz(sr + 64, skc);
    for (int ks = 0; ks < KSTEPS; ++ks) {
        {
            f16x8 h; float xv[8];
            *(float4*)(&xv[0]) = ra[0]; *(float4*)(&xv[4]) = ra[1];
#pragma unroll
            for (int e = 0; e < 8; ++e) h[e] = (_Float16)xv[e];
            *(f16x8*)(&Ah[wA0]) = h;
            *(float4*)(&xv[0]) = ra[2]; *(float4*)(&xv[4]) = ra[3];
#pragma unroll
            for (int e = 0; e < 8; ++e) h[e] = (_Float16)xv[e];
            *(f16x8*)(&Ah[wA1]) = h;
            *(float4*)(&xv[0]) = rb[0]; *(float4*)(&xv[4]) = rb[1];
#pragma unroll
            for (int e = 0; e < 8; ++e) h[e] = (_Float16)xv[e];
            *(f16x8*)(&Bh[wA0]) = h;
            *(float4*)(&xv[0]) = rb[2]; *(float4*)(&xv[4]) = rb[3];
#pragma unroll
            for (int e = 0; e < 8; ++e) h[e] = (_Float16)xv[e];
            *(f16x8*)(&Bh[wA1]) = h;
        }
        __syncthreads();
        if (ks + 1 < KSTEPS) {
            const int ko = (ks + 1) * BK;
            ra[0] = *(const float4*)(Aptr0 + ko); ra[1] = *(const float4*)(Aptr0 + ko + 4);
            ra[2] = *(const float4*)(Aptr1 + ko); ra[3] = *(const float4*)(Aptr1 + ko + 4);
            rb[0] = *(const float4*)(Bptr0 + ko); rb[1] = *(const float4*)(Bptr0 + ko + 4);
            rb[2] = *(const float4*)(Bptr1 + ko); rb[3] = *(const float4*)(Bptr1 + ko + 4);
        }
        f16x8 bhf[4];
#pragma unroll
        for (int j = 0; j < 4; ++j)
            bhf[j] = *(const f16x8*)(&Bh[swz(wn * 64 + j * 16 + lr, kg)]);
#pragma unroll
        for (int i = 0; i < 4; ++i) {
            f16x8 ahf = *(const f16x8*)(&Ah[swz(wm * 64 + i * 16 + lr, kg)]);
#pragma unroll
            for (int j = 0; j < 4; ++j)
                acc[i][j] = __builtin_amdgcn_mfma_f32_16x16x32_f16(ahf, bhf[j], acc[i][j], 0, 0, 0);
        }
        __syncthreads();
    }
    float inv[4];
#pragma unroll
    for (int j = 0; j < 4; ++j) inv[j] = invnorm[n0 + wn * 64 + j * 16 + lr];
#pragma unroll
    for (int i = 0; i < 4; ++i) {
#pragma unroll
        for (int r = 0; r < 4; ++r) {
            u64 k[4];
#pragma unroll
            for (int j = 0; j < 4; ++j)
                k[j] = pack_key(acc[i][j][r] * inv[j],
                                (unsigned int)(n0 + wn * 64 + j * 16 + lr));
            u64 m01 = umax64(k[0], k[1]), n01 = umin64(k[0], k[1]);
            u64 m23 = umax64(k[2], k[3]), n23 = umin64(k[2], k[3]);
            u64 a1 = umax64(m01, m23);
            u64 a2 = umax64(umin64(m01, m23), umax64(n01, n23));
#pragma unroll
            for (int mask = 1; mask < 16; mask <<= 1) {
                u64 b1 = __shfl_xor(a1, mask);
                u64 b2 = __shfl_xor(a2, mask);
                u64 t1 = umax64(a1, b1);
                a2 = umax64(umin64(a1, b1), umax64(a2, b2));
                a1 = t1;
            }
            if (lr == 0) {
                const int row = m0 + wm * 64 + i * 16 + kg * 4 + r;
                cascade3(&R1[row], &R2[row], &R3[row], a1);
                cascade3(&R1[row], &R2[row], &R3[row], a2);
            }
        }
    }
}

// block-wide sum reduction; returns total to ALL threads
__device__ __forceinline__ float block_sum(float v, float* sbuf, int t) {
#pragma unroll
    for (int off = 32; off > 0; off >>= 1) v += __shfl_down(v, off);
    const int lane = t & 63, w = t >> 6;
    __syncthreads();
    if (lane == 0) sbuf[w] = v;
    __syncthreads();
    return sbuf[0] + sbuf[1] + sbuf[2] + sbuf[3];
}

__global__ void rescue_finalize_kernel(const float* __restrict__ X,
                                       const float* __restrict__ Vg,
                                       const u64* __restrict__ R1,
                                       const u64* __restrict__ R2,
                                       const u64* __restrict__ R3,
                                       float* __restrict__ outx,
                                       float* __restrict__ outid) {
    const int row = blockIdx.x;
    const int t = threadIdx.x;
    __shared__ float sbuf[4];

    int cand[3];
    cand[0] = (int)(~(unsigned int)(R1[row] & 0xFFFFFFFFull));
    cand[1] = (int)(~(unsigned int)(R2[row] & 0xFFFFFFFFull));
    cand[2] = (int)(~(unsigned int)(R3[row] & 0xFFFFFFFFull));

    const float* x = X + (size_t)row * DIM;
    float4 x0 = *reinterpret_cast<const float4*>(x + t * 8);
    float4 x1 = *reinterpret_cast<const float4*>(x + t * 8 + 4);
    float xxp = x0.x*x0.x + x0.y*x0.y + x0.z*x0.z + x0.w*x0.w
              + x1.x*x1.x + x1.y*x1.y + x1.z*x1.z + x1.w*x1.w;
    const float xx = block_sum(xxp, sbuf, t);
    const float xn = fmaxf(sqrtf(xx), 1e-12f);

    u64 bestkey = 0ull;
    int bestid = cand[0];
    float bestsa = 0.f;
#pragma unroll
    for (int c = 0; c < 3; ++c) {
        const float* v = Vg + (size_t)cand[c] * DIM;
        float4 v0 = *reinterpret_cast<const float4*>(v + t * 8);
        float4 v1 = *reinterpret_cast<const float4*>(v + t * 8 + 4);
        float dp = x0.x*v0.x + x0.y*v0.y + x0.z*v0.z + x0.w*v0.w
                 + x1.x*v1.x + x1.y*v1.y + x1.z*v1.z + x1.w*v1.w;
        float vp = v0.x*v0.x + v0.y*v0.y + v0.z*v0.z + v0.w*v0.w
                 + v1.x*v1.x + v1.y*v1.y + v1.z*v1.z + v1.w*v1.w;
        const float dot = block_sum(dp, sbuf, t);
        const float vv  = block_sum(vp, sbuf, t);
        const float s = dot / (xn * fmaxf(sqrtf(vv), 1e-12f));
        u64 key = pack_key(s, (unsigned int)cand[c]);
        if (key > bestkey) { bestkey = key; bestid = cand[c]; bestsa = vv; }
    }

    const float* a = Vg + (size_t)bestid * DIM;
    float4 a0 = *reinterpret_cast<const float4*>(a + t * 8);
    float4 a1 = *reinterpret_cast<const float4*>(a + t * 8 + 4);
    float4 d0 = make_float4(x0.x-a0.x, x0.y-a0.y, x0.z-a0.z, x0.w-a0.w);
    float4 d1 = make_float4(x1.x-a1.x, x1.y-a1.y, x1.z-a1.z, x1.w-a1.w);
    float sop = d0.x*d0.x + d0.y*d0.y + d0.z*d0.z + d0.w*d0.w
              + d1.x*d1.x + d1.y*d1.y + d1.z*d1.z + d1.w*d1.w;
    const float so = block_sum(sop, sbuf, t);
    const float scale = fminf(0.1f * sqrtf(bestsa) / (sqrtf(so) + 1e-8f), 1.0f);

    float4 o0 = make_float4(a0.x + d0.x*scale, a0.y + d0.y*scale,
                            a0.z + d0.z*scale, a0.w + d0.w*scale);
    float4 o1 = make_float4(a1.x + d1.x*scale, a1.y + d1.y*scale,
                            a1.z + d1.z*scale, a1.w + d1.w*scale);
    float* o = outx + (size_t)row * DIM + t * 8;
    *reinterpret_cast<float4*>(o)     = o0;
    *reinterpret_cast<float4*>(o + 4) = o1;
    if (t == 0) outid[row] = (float)bestid;
}

extern "C" void kernel_launch(void* const* d_in, const int* in_sizes, int n_in,
                              void* d_out, int out_size, void* d_ws, size_t ws_size,
                              hipStream_t stream) {
    const float* X  = (const float*)d_in[0];
    const float* Vg = (const float*)d_in[1];
    const int M  = in_sizes[0] / DIM;   // 8192
    const int NV = in_sizes[1] / DIM;   // 32000

    char* ws = (char*)d_ws;
    u64* R1 = (u64*)ws;
    u64* R2 = R1 + M;
    u64* R3 = R2 + M;
    size_t off = (size_t)3 * M * sizeof(u64);            // 196608
    float* invnorm = (float*)(ws + off);
    off += ((size_t)NV * sizeof(float) + 255) & ~255ull; // 128256
    _Float16* Xh = (_Float16*)(ws + off);
    off += (size_t)M * DIM * sizeof(_Float16);           // 32 MB
    _Float16* Vh = (_Float16*)(ws + off);
    off += (size_t)NV * DIM * sizeof(_Float16);          // 128 MB
    const bool fast = (ws_size >= off);

    float* outx  = (float*)d_out;
    float* outid = outx + (size_t)M * DIM;

    hipMemsetAsync(R1, 0, (size_t)3 * M * sizeof(u64), stream);
    vocab_invnorm_kernel<<<NV, 256, 0, stream>>>(Vg, invnorm);

    if (fast) {
        convert_x_kernel<<<(M / BM) * KSTEPS, 256, 0, stream>>>(X, Xh);
        convert_v_kernel<<<(NV / BN) * KSTEPS, 256, 0, stream>>>(Vg, invnorm, Vh);
        dim3 grid((NV / BN) * (M / BM));    // 125*32 = 4000 blocks
        sim_f16_phased<<<grid, 512, 0, stream>>>(Xh, Vh, R1, R2, R3);
    } else {
        dim3 gridf((NV / 128) * (M / 128)); // 16000 blocks
        sim_coarse_fallback<<<gridf, 256, 0, stream>>>(X, Vg, invnorm, R1, R2, R3);
    }

    rescue_finalize_kernel<<<M, 256, 0, stream>>>(X, Vg, R1, R2, R3, outx, outid);
}

// Round 9
// 1726.776 us; speedup vs baseline: 1.1979x; 1.1979x over previous
//
#include <hip/hip_runtime.h>
#include <hip/hip_bf16.h>

#define DIM 2048
#define BM 128
#define BN 256
#define BK 32
#define KSTEPS (DIM / BK)          // 64 K-tiles
#define A_TILE_ELEMS (BM * BK)     // 4096 f16 = 8 KB
#define B_TILE_ELEMS (BN * BK)     // 8192 f16 = 16 KB

typedef _Float16 f16x8 __attribute__((ext_vector_type(8)));
typedef float f32x4 __attribute__((ext_vector_type(4)));
typedef unsigned long long u64;

typedef const unsigned int __attribute__((address_space(1))) gu32;
typedef unsigned int __attribute__((address_space(3))) lu32;

__device__ __forceinline__ void gl_lds16(const void* g, void* l) {
    __builtin_amdgcn_global_load_lds((gu32*)g, (lu32*)l, 16, 0, 0);
}

// Monotone float->uint map; pack (val, col) so u64 max = (max val, first col on ties)
__device__ __forceinline__ u64 pack_key(float v, unsigned int col) {
    unsigned int b = __float_as_uint(v);
    b ^= (unsigned int)(((int)b >> 31)) | 0x80000000u;
    return ((u64)b << 32) | (u64)(~col);
}
__device__ __forceinline__ u64 umax64(u64 a, u64 b) { return a > b ? a : b; }
__device__ __forceinline__ u64 umin64(u64 a, u64 b) { return a < b ? a : b; }

// lock-free exact top-3 cascade (order-independent => deterministic)
__device__ __forceinline__ void cascade3(u64* r1, u64* r2, u64* r3, u64 k) {
    u64 old = atomicMax(r1, k);
    k = umin64(k, old);
    if (k) {
        old = atomicMax(r2, k);
        k = umin64(k, old);
        if (k) atomicMax(r3, k);
    }
}

// tile image: 128B lines (row pairs), 8x16B slots, slot ^= line&7 (0 conflicts, r6/r7-verified)
__device__ __forceinline__ int tileoff(int row, int kg) {
    const int line = row >> 1;
    const int s8 = ((row & 1) << 2) | kg;
    return line * 64 + ((s8 ^ (line & 7)) << 3);
}

// old swizzle (used by the 128^2 fallback kernel only)
__device__ __forceinline__ int swz(int row, int slot) {
    return row * BK + (slot ^ ((row >> 1) & 3)) * 8;
}

__global__ void vocab_invnorm_kernel(const float* __restrict__ Vg,
                                     float* __restrict__ invnorm) {
    const int v = blockIdx.x;
    const int t = threadIdx.x;
    const float* row = Vg + (size_t)v * DIM;
    float4 f0 = *reinterpret_cast<const float4*>(row + t * 8);
    float4 f1 = *reinterpret_cast<const float4*>(row + t * 8 + 4);
    float s = f0.x*f0.x + f0.y*f0.y + f0.z*f0.z + f0.w*f0.w
            + f1.x*f1.x + f1.y*f1.y + f1.z*f1.z + f1.w*f1.w;
#pragma unroll
    for (int off = 32; off > 0; off >>= 1) s += __shfl_down(s, off);
    __shared__ float ls[4];
    const int lane = t & 63, w = t >> 6;
    if (lane == 0) ls[w] = s;
    __syncthreads();
    if (t == 0) {
        float tot = ls[0] + ls[1] + ls[2] + ls[3];
        invnorm[v] = 1.0f / fmaxf(sqrtf(tot), 1e-12f);
    }
}

// X -> tiled f16 in the line/slot-swizzled image (raw values), tile = [128][32]
__global__ void convert_x_kernel(const float* __restrict__ X, _Float16* __restrict__ Xh) {
    const int tile = blockIdx.x;          // mblk*64 + ks
    const int mblk = tile >> 6, ks = tile & 63;
    const float* src = X + (size_t)(mblk * BM) * DIM + ks * BK;
    _Float16* dst = Xh + (size_t)tile * A_TILE_ELEMS;
    const int t = threadIdx.x;
#pragma unroll
    for (int u = 0; u < 2; ++u) {
        const int c = t + u * 256;        // 0..511 chunk id (linear stage order)
        const int line = c >> 3;
        const int s8 = (c & 7) ^ (line & 7);
        const int row = (line << 1) | (s8 >> 2);
        const int cs = s8 & 3;
        const float* s = src + (size_t)row * DIM + cs * 8;
        float4 f0 = *(const float4*)s, f1 = *(const float4*)(s + 4);
        float xv[8] = {f0.x, f0.y, f0.z, f0.w, f1.x, f1.y, f1.z, f1.w};
        f16x8 h;
#pragma unroll
        for (int e = 0; e < 8; ++e) h[e] = (_Float16)xv[e];
        *(f16x8*)(dst + c * 8) = h;
    }
}

// V -> tiled f16 (same image), pre-normalized by invnorm, tile = [256][32]
__global__ void convert_v_kernel(const float* __restrict__ Vg,
                                 const float* __restrict__ invnorm,
                                 _Float16* __restrict__ Vh) {
    const int tile = blockIdx.x;          // nblk*64 + ks
    const int nblk = tile >> 6, ks = tile & 63;
    const float* src = Vg + (size_t)(nblk * BN) * DIM + ks * BK;
    _Float16* dst = Vh + (size_t)tile * B_TILE_ELEMS;
    const int t = threadIdx.x;
#pragma unroll
    for (int u = 0; u < 4; ++u) {
        const int c = t + u * 256;        // 0..1023
        const int line = c >> 3;
        const int s8 = (c & 7) ^ (line & 7);
        const int row = (line << 1) | (s8 >> 2);
        const int cs = s8 & 3;
        const float sc = invnorm[nblk * BN + row];
        const float* s = src + (size_t)row * DIM + cs * 8;
        float4 f0 = *(const float4*)s, f1 = *(const float4*)(s + 4);
        float xv[8] = {f0.x, f0.y, f0.z, f0.w, f1.x, f1.y, f1.z, f1.w};
        f16x8 h;
#pragma unroll
        for (int e = 0; e < 8; ++e) h[e] = (_Float16)(xv[e] * sc);
        *(f16x8*)(dst + c * 8) = h;
    }
}

// 512 threads = 8 waves (2M x 4N), wave tile 64x64, block tile 128x256.
// Double-buffered LDS (48 KB) + <=128 VGPR => TWO blocks co-resident per CU:
// inter-block overlap hides ds_read bursts and barrier drains (m114 regime).
__global__ __launch_bounds__(512, 4) void sim_f16_dual(
        const _Float16* __restrict__ Xh, const _Float16* __restrict__ Vh,
        u64* __restrict__ R1, u64* __restrict__ R2, u64* __restrict__ R3) {
    __shared__ alignas(16) _Float16 ldsA[2][A_TILE_ELEMS];   // 16 KB
    __shared__ alignas(16) _Float16 ldsB[2][B_TILE_ELEMS];   // 32 KB

    const int tid = threadIdx.x;
    // XCD-chunked bijective swizzle: 8000 blocks = 8 x 1000; m-fastest in chunk
    const int flat = blockIdx.x;
    const int idx  = (flat & 7) * 1000 + (flat >> 3);
    const int mblk = idx & 63;           // M/128 = 64
    const int nblk = idx >> 6;           // NV/256 = 125

    const int lane = tid & 63;
    const int w  = tid >> 6;             // 0..7
    const int wm = w >> 2, wn = w & 3;   // 2x4 wave grid; wave tile 64x64
    const int lr = lane & 15;
    const int kg = lane >> 4;

    const _Float16* Atiles = Xh + (size_t)mblk * KSTEPS * A_TILE_ELEMS;
    const _Float16* Btiles = Vh + (size_t)nblk * KSTEPS * B_TILE_ELEMS;

    f32x4 acc[4][4] = {};

    int offA[4], offB[4];
#pragma unroll
    for (int i = 0; i < 4; ++i) offA[i] = tileoff(wm * 64 + i * 16 + lr, kg);
#pragma unroll
    for (int j = 0; j < 4; ++j) offB[j] = tileoff(wn * 64 + j * 16 + lr, kg);

    const int cA = tid * 8;              // A: 512 chunks, 1 per thread
    const int cB1 = tid * 8;             // B: 1024 chunks, 2 per thread
    const int cB2 = (tid + 512) * 8;

    // prologue: stage K-tile 0 into buffer 0
    gl_lds16(Atiles + cA,  &ldsA[0][cA]);
    gl_lds16(Btiles + cB1, &ldsB[0][cB1]);
    gl_lds16(Btiles + cB2, &ldsB[0][cB2]);
    __syncthreads();

    int cur = 0;
    for (int ks = 0; ks < KSTEPS; ++ks) {
        if (ks + 1 < KSTEPS) {   // stage next K-tile into other buffer (in flight across compute)
            const _Float16* an = Atiles + (size_t)(ks + 1) * A_TILE_ELEMS;
            const _Float16* bn = Btiles + (size_t)(ks + 1) * B_TILE_ELEMS;
            gl_lds16(an + cA,  &ldsA[cur ^ 1][cA]);
            gl_lds16(bn + cB1, &ldsB[cur ^ 1][cB1]);
            gl_lds16(bn + cB2, &ldsB[cur ^ 1][cB2]);
        }
        f16x8 bhf[4];
#pragma unroll
        for (int j = 0; j < 4; ++j) bhf[j] = *(const f16x8*)(&ldsB[cur][offB[j]]);
#pragma unroll
        for (int i = 0; i < 4; ++i) {
            f16x8 ahf = *(const f16x8*)(&ldsA[cur][offA[i]]);
#pragma unroll
            for (int j = 0; j < 4; ++j)
                acc[i][j] = __builtin_amdgcn_mfma_f32_16x16x32_f16(ahf, bhf[j], acc[i][j], 0, 0, 0);
        }
        __syncthreads();   // drains vmcnt (next tile landed) + lgkm; protects dbuf WAR
        cur ^= 1;
    }

    // epilogue: per-row top-2 within wave cols -> global top-3 cascade
    const int m0 = mblk * BM, n0 = nblk * BN;
#pragma unroll
    for (int i = 0; i < 4; ++i) {
#pragma unroll
        for (int r = 0; r < 4; ++r) {
            u64 k[4];
#pragma unroll
            for (int j = 0; j < 4; ++j)
                k[j] = pack_key(acc[i][j][r],
                                (unsigned int)(n0 + wn * 64 + j * 16 + lr));
            u64 m01 = umax64(k[0], k[1]), n01 = umin64(k[0], k[1]);
            u64 m23 = umax64(k[2], k[3]), n23 = umin64(k[2], k[3]);
            u64 a1 = umax64(m01, m23);
            u64 a2 = umax64(umin64(m01, m23), umax64(n01, n23));
#pragma unroll
            for (int mask = 1; mask < 16; mask <<= 1) {
                u64 b1 = __shfl_xor(a1, mask);
                u64 b2 = __shfl_xor(a2, mask);
                u64 t1 = umax64(a1, b1);
                a2 = umax64(umin64(a1, b1), umax64(a2, b2));
                a1 = t1;
            }
            if (lr == 0) {
                const int row = m0 + wm * 64 + i * 16 + kg * 4 + r;
                cascade3(&R1[row], &R2[row], &R3[row], a1);
                cascade3(&R1[row], &R2[row], &R3[row], a2);
            }
        }
    }
}

// ---------------- fallback (verified round-3 path, 128^2; used if ws too small) ----------------
__global__ __launch_bounds__(256) void sim_coarse_fallback(
        const float* __restrict__ X, const float* __restrict__ Vg,
        const float* __restrict__ invnorm,
        u64* __restrict__ R1, u64* __restrict__ R2, u64* __restrict__ R3) {
    __shared__ alignas(16) _Float16 Ah[128 * BK];
    __shared__ alignas(16) _Float16 Bh[128 * BK];
    const int tid = threadIdx.x;
    const int flat = blockIdx.x;
    const int idx  = (flat & 7) * 2000 + (flat >> 3);
    const int panel = idx / 3200;
    const int w_    = idx - panel * 3200;
    const int mblk  = w_ & 63;
    const int nblk  = panel * 50 + (w_ >> 6);
    const int m0 = mblk * 128, n0 = nblk * 128;
    const int lane = tid & 63;
    const int w  = tid >> 6;
    const int wm = w >> 1, wn = w & 1;
    const int lr = lane & 15;
    const int kg = lane >> 4;
    const int sr  = tid >> 2;
    const int skc = tid & 3;
    const float* Aptr0 = X  + (size_t)(m0 + sr)      * DIM + skc * 8;
    const float* Aptr1 = X  + (size_t)(m0 + 64 + sr) * DIM + skc * 8;
    const float* Bptr0 = Vg + (size_t)(n0 + sr)      * DIM + skc * 8;
    const float* Bptr1 = Vg + (size_t)(n0 + 64 + sr) * DIM + skc * 8;
    float4 ra[4], rb[4];
    ra[0] = *(const float4*)(Aptr0);     ra[1] = *(const float4*)(Aptr0 + 4);
    ra[2] = *(const float4*)(Aptr1);     ra[3] = *(const float4*)(Aptr1 + 4);
    rb[0] = *(const float4*)(Bptr0);     rb[1] = *(const float4*)(Bptr0 + 4);
    rb[2] = *(const float4*)(Bptr1);     rb[3] = *(const float4*)(Bptr1 + 4);
    f32x4 acc[4][4] = {};
    const int wA0 = swz(sr, skc), wA1 = swz(sr + 64, skc);
    for (int ks = 0; ks < KSTEPS; ++ks) {
        {
            f16x8 h; float xv[8];
            *(float4*)(&xv[0]) = ra[0]; *(float4*)(&xv[4]) = ra[1];
#pragma unroll
            for (int e = 0; e < 8; ++e) h[e] = (_Float16)xv[e];
            *(f16x8*)(&Ah[wA0]) = h;
            *(float4*)(&xv[0]) = ra[2]; *(float4*)(&xv[4]) = ra[3];
#pragma unroll
            for (int e = 0; e < 8; ++e) h[e] = (_Float16)xv[e];
            *(f16x8*)(&Ah[wA1]) = h;
            *(float4*)(&xv[0]) = rb[0]; *(float4*)(&xv[4]) = rb[1];
#pragma unroll
            for (int e = 0; e < 8; ++e) h[e] = (_Float16)xv[e];
            *(f16x8*)(&Bh[wA0]) = h;
            *(float4*)(&xv[0]) = rb[2]; *(float4*)(&xv[4]) = rb[3];
#pragma unroll
            for (int e = 0; e < 8; ++e) h[e] = (_Float16)xv[e];
            *(f16x8*)(&Bh[wA1]) = h;
        }
        __syncthreads();
        if (ks + 1 < KSTEPS) {
            const int ko = (ks + 1) * BK;
            ra[0] = *(const float4*)(Aptr0 + ko); ra[1] = *(const float4*)(Aptr0 + ko + 4);
            ra[2] = *(const float4*)(Aptr1 + ko); ra[3] = *(const float4*)(Aptr1 + ko + 4);
            rb[0] = *(const float4*)(Bptr0 + ko); rb[1] = *(const float4*)(Bptr0 + ko + 4);
            rb[2] = *(const float4*)(Bptr1 + ko); rb[3] = *(const float4*)(Bptr1 + ko + 4);
        }
        f16x8 bhf[4];
#pragma unroll
        for (int j = 0; j < 4; ++j)
            bhf[j] = *(const f16x8*)(&Bh[swz(wn * 64 + j * 16 + lr, kg)]);
#pragma unroll
        for (int i = 0; i < 4; ++i) {
            f16x8 ahf = *(const f16x8*)(&Ah[swz(wm * 64 + i * 16 + lr, kg)]);
#pragma unroll
            for (int j = 0; j < 4; ++j)
                acc[i][j] = __builtin_amdgcn_mfma_f32_16x16x32_f16(ahf, bhf[j], acc[i][j], 0, 0, 0);
        }
        __syncthreads();
    }
    float inv[4];
#pragma unroll
    for (int j = 0; j < 4; ++j) inv[j] = invnorm[n0 + wn * 64 + j * 16 + lr];
#pragma unroll
    for (int i = 0; i < 4; ++i) {
#pragma unroll
        for (int r = 0; r < 4; ++r) {
            u64 k[4];
#pragma unroll
            for (int j = 0; j < 4; ++j)
                k[j] = pack_key(acc[i][j][r] * inv[j],
                                (unsigned int)(n0 + wn * 64 + j * 16 + lr));
            u64 m01 = umax64(k[0], k[1]), n01 = umin64(k[0], k[1]);
            u64 m23 = umax64(k[2], k[3]), n23 = umin64(k[2], k[3]);
            u64 a1 = umax64(m01, m23);
            u64 a2 = umax64(umin64(m01, m23), umax64(n01, n23));
#pragma unroll
            for (int mask = 1; mask < 16; mask <<= 1) {
                u64 b1 = __shfl_xor(a1, mask);
                u64 b2 = __shfl_xor(a2, mask);
                u64 t1 = umax64(a1, b1);
                a2 = umax64(umin64(a1, b1), umax64(a2, b2));
                a1 = t1;
            }
            if (lr == 0) {
                const int row = m0 + wm * 64 + i * 16 + kg * 4 + r;
                cascade3(&R1[row], &R2[row], &R3[row], a1);
                cascade3(&R1[row], &R2[row], &R3[row], a2);
            }
        }
    }
}

// block-wide sum reduction; returns total to ALL threads
__device__ __forceinline__ float block_sum(float v, float* sbuf, int t) {
#pragma unroll
    for (int off = 32; off > 0; off >>= 1) v += __shfl_down(v, off);
    const int lane = t & 63, w = t >> 6;
    __syncthreads();
    if (lane == 0) sbuf[w] = v;
    __syncthreads();
    return sbuf[0] + sbuf[1] + sbuf[2] + sbuf[3];
}

__global__ void rescue_finalize_kernel(const float* __restrict__ X,
                                       const float* __restrict__ Vg,
                                       const u64* __restrict__ R1,
                                       const u64* __restrict__ R2,
                                       const u64* __restrict__ R3,
                                       float* __restrict__ outx,
                                       float* __restrict__ outid) {
    const int row = blockIdx.x;
    const int t = threadIdx.x;
    __shared__ float sbuf[4];

    int cand[3];
    cand[0] = (int)(~(unsigned int)(R1[row] & 0xFFFFFFFFull));
    cand[1] = (int)(~(unsigned int)(R2[row] & 0xFFFFFFFFull));
    cand[2] = (int)(~(unsigned int)(R3[row] & 0xFFFFFFFFull));

    const float* x = X + (size_t)row * DIM;
    float4 x0 = *reinterpret_cast<const float4*>(x + t * 8);
    float4 x1 = *reinterpret_cast<const float4*>(x + t * 8 + 4);
    float xxp = x0.x*x0.x + x0.y*x0.y + x0.z*x0.z + x0.w*x0.w
              + x1.x*x1.x + x1.y*x1.y + x1.z*x1.z + x1.w*x1.w;
    const float xx = block_sum(xxp, sbuf, t);
    const float xn = fmaxf(sqrtf(xx), 1e-12f);

    u64 bestkey = 0ull;
    int bestid = cand[0];
    float bestsa = 0.f;
#pragma unroll
    for (int c = 0; c < 3; ++c) {
        const float* v = Vg + (size_t)cand[c] * DIM;
        float4 v0 = *reinterpret_cast<const float4*>(v + t * 8);
        float4 v1 = *reinterpret_cast<const float4*>(v + t * 8 + 4);
        float dp = x0.x*v0.x + x0.y*v0.y + x0.z*v0.z + x0.w*v0.w
                 + x1.x*v1.x + x1.y*v1.y + x1.z*v1.z + x1.w*v1.w;
        float vp = v0.x*v0.x + v0.y*v0.y + v0.z*v0.z + v0.w*v0.w
                 + v1.x*v1.x + v1.y*v1.y + v1.z*v1.z + v1.w*v1.w;
        const float dot = block_sum(dp, sbuf, t);
        const float vv  = block_sum(vp, sbuf, t);
        const float s = dot / (xn * fmaxf(sqrtf(vv), 1e-12f));
        u64 key = pack_key(s, (unsigned int)cand[c]);
        if (key > bestkey) { bestkey = key; bestid = cand[c]; bestsa = vv; }
    }

    const float* a = Vg + (size_t)bestid * DIM;
    float4 a0 = *reinterpret_cast<const float4*>(a + t * 8);
    float4 a1 = *reinterpret_cast<const float4*>(a + t * 8 + 4);
    float4 d0 = make_float4(x0.x-a0.x, x0.y-a0.y, x0.z-a0.z, x0.w-a0.w);
    float4 d1 = make_float4(x1.x-a1.x, x1.y-a1.y, x1.z-a1.z, x1.w-a1.w);
    float sop = d0.x*d0.x + d0.y*d0.y + d0.z*d0.z + d0.w*d0.w
              + d1.x*d1.x + d1.y*d1.y + d1.z*d1.z + d1.w*d1.w;
    const float so = block_sum(sop, sbuf, t);
    const float scale = fminf(0.1f * sqrtf(bestsa) / (sqrtf(so) + 1e-8f), 1.0f);

    float4 o0 = make_float4(a0.x + d0.x*scale, a0.y + d0.y*scale,
                            a0.z + d0.z*scale, a0.w + d0.w*scale);
    float4 o1 = make_float4(a1.x + d1.x*scale, a1.y + d1.y*scale,
                            a1.z + d1.z*scale, a1.w + d1.w*scale);
    float* o = outx + (size_t)row * DIM + t * 8;
    *reinterpret_cast<float4*>(o)     = o0;
    *reinterpret_cast<float4*>(o + 4) = o1;
    if (t == 0) outid[row] = (float)bestid;
}

extern "C" void kernel_launch(void* const* d_in, const int* in_sizes, int n_in,
                              void* d_out, int out_size, void* d_ws, size_t ws_size,
                              hipStream_t stream) {
    const float* X  = (const float*)d_in[0];
    const float* Vg = (const float*)d_in[1];
    const int M  = in_sizes[0] / DIM;   // 8192
    const int NV = in_sizes[1] / DIM;   // 32000

    char* ws = (char*)d_ws;
    u64* R1 = (u64*)ws;
    u64* R2 = R1 + M;
    u64* R3 = R2 + M;
    size_t off = (size_t)3 * M * sizeof(u64);            // 196608
    float* invnorm = (float*)(ws + off);
    off += ((size_t)NV * sizeof(float) + 255) & ~255ull; // 128256
    _Float16* Xh = (_Float16*)(ws + off);
    off += (size_t)M * DIM * sizeof(_Float16);           // 32 MB
    _Float16* Vh = (_Float16*)(ws + off);
    off += (size_t)NV * DIM * sizeof(_Float16);          // 128 MB
    const bool fast = (ws_size >= off);

    float* outx  = (float*)d_out;
    float* outid = outx + (size_t)M * DIM;

    hipMemsetAsync(R1, 0, (size_t)3 * M * sizeof(u64), stream);
    vocab_invnorm_kernel<<<NV, 256, 0, stream>>>(Vg, invnorm);

    if (fast) {
        convert_x_kernel<<<(M / BM) * KSTEPS, 256, 0, stream>>>(X, Xh);   // 64*64 = 4096
        convert_v_kernel<<<(NV / BN) * KSTEPS, 256, 0, stream>>>(Vg, invnorm, Vh); // 125*64 = 8000
        dim3 grid((NV / BN) * (M / BM));    // 125*64 = 8000 blocks
        sim_f16_dual<<<grid, 512, 0, stream>>>(Xh, Vh, R1, R2, R3);
    } else {
        dim3 gridf((NV / 128) * (M / 128)); // 16000 blocks
        sim_coarse_fallback<<<gridf, 256, 0, stream>>>(X, Vg, invnorm, R1, R2, R3);
    }

    rescue_finalize_kernel<<<M, 256, 0, stream>>>(X, Vg, R1, R2, R3, outx, outid);
}